// Round 8
// baseline (155.282 us; speedup 1.0000x reference)
//
#include <hip/hip_runtime.h>
#include <hip/hip_bf16.h>

#define RANK 16
#define BATCH 32768
#define K_DIM 4096   // A1*B1
#define N_DIM 64     // A2*B2
#define CHUNK 128    // K floats per chunk = 512B per row
#define NCHUNK 32    // 4096/128
#define ROWB 128     // rows per block

typedef __bf16 bf16x8 __attribute__((ext_vector_type(8)));
typedef float floatx4 __attribute__((ext_vector_type(4)));
typedef unsigned short ushort8 __attribute__((ext_vector_type(8)));

#define WAITVM(n) asm volatile("s_waitcnt vmcnt(" #n ")" ::: "memory")
#define BARRIER() asm volatile("s_barrier" ::: "memory")

__device__ inline unsigned short f2bf(float f) {
  unsigned u = __builtin_bit_cast(unsigned, f);
  u += 0x7fffu + ((u >> 16) & 1u);   // round-to-nearest-even
  return (unsigned short)(u >> 16);
}

__device__ inline bf16x8 cvt8(float4 a0, float4 a1) {
  ushort8 au;
  au[0] = f2bf(a0.x); au[1] = f2bf(a0.y); au[2] = f2bf(a0.z); au[3] = f2bf(a0.w);
  au[4] = f2bf(a1.x); au[5] = f2bf(a1.y); au[6] = f2bf(a1.z); au[7] = f2bf(a1.w);
  return __builtin_bit_cast(bf16x8, au);
}

// Fragment-major w for the 16x16x32 B-operand (layout unchanged):
//   wF[((cg*128 + ks)*64 + lane)*8 + j] = w[k][n],
//   n = cg*16 + (lane&15), k = ks*32 + (lane>>4)*8 + j.
__global__ __launch_bounds__(256) void build_wF(
    const float* __restrict__ s, const float* __restrict__ a,
    const float* __restrict__ b, unsigned short* __restrict__ wF) {
  int e = blockIdx.x * 256 + threadIdx.x;   // 0 .. 262143
  int j    = e & 7;
  int lane = (e >> 3) & 63;
  int ks   = (e >> 9) & 127;
  int cg   = e >> 16;
  int n = cg * 16 + (lane & 15);
  int k = ks * 32 + ((lane >> 4) << 3) + j;
  int i = k >> 6, kk = k & 63, jj = n >> 3, ll = n & 7;
  float acc = 0.f;
  #pragma unroll
  for (int r = 0; r < RANK; ++r) {
    acc += a[r * 512 + i * 8 + jj] * b[r * 512 + kk * 8 + ll];
  }
  acc *= s[i * 8 + jj];
  wF[e] = f2bf(acc);
}

// Block = 128 rows x 64 cols, 4 waves; wave = ONE col-group (16 cols) x
// all 128 rows (8 A-frags of 16x16x32). w loaded once per block (zero
// duplication) -> per-block vmem = x 2MB + w 0.5MB; chip total 0.65GB
// (r7: 0.78GB) against the ~13 B/cyc/CU vmem-port ceiling identified in
// r6/r7. 1 block/CU (128KB LDS), latency hidden by the depth-2 counted
// ring: per chunk 20 vmem ops/wave (4 w-reg + 16 gll), WAITVM(20) keeps
// the next chunk fully in flight, compute issues no vmem. XOR swizzle
// on global source + ds_read side (both-sides rule). Epilogue bounces
// acc through LDS so the block's 32KB out-slab is written as pure
// coalesced float4 streams (fixes 64-lines-per-store scatter).
__global__ __launch_bounds__(256, 1) void kron_gemm(
    const float* __restrict__ x, const unsigned short* __restrict__ wF,
    const float* __restrict__ bias, float* __restrict__ out) {
  __shared__ __align__(16) float As[2][ROWB * CHUNK];   // 2 x 64 KB

  const int tid  = threadIdx.x;
  const int lane = tid & 63;
  const int wave = tid >> 6;     // = col-group cg
  const int ln15 = lane & 15;
  const int kseg = lane >> 4;
  const int m0   = blockIdx.x * ROWB;
  const int rhalf = lane >> 5;   // staging: row within the 1KB pair

  floatx4 acc[8] = {};

  struct W4 { bf16x8 t[4]; };

  auto loadw = [&](int c) {
    W4 w;
    #pragma unroll
    for (int t = 0; t < 4; ++t)
      w.t[t] = *(const bf16x8*)(wF + (((size_t)(wave * 128 + c * 4 + t)) << 9)
                                + (lane << 3));
    return w;
  };

  // stage chunk c: 16 gll instrs/wave, each 1KB = 2 rows x 512B
  auto stage = [&](float* buf, int c) {
    #pragma unroll
    for (int p = 0; p < 16; ++p) {
      const int rbase = wave * 32 + 2 * p;               // wave-uniform
      const int row   = rbase + rhalf;                   // per-lane
      const int sb    = ((lane & 31) << 4) ^ ((row & 7) << 4);
      const float* src = x + (size_t)(m0 + row) * K_DIM + c * CHUNK + (sb >> 2);
      float* dst = buf + rbase * CHUNK;
      __builtin_amdgcn_global_load_lds(
          (const __attribute__((address_space(1))) void*)(const void*)src,
          (__attribute__((address_space(3))) void*)(void*)dst, 16, 0, 0);
    }
  };

  auto compute = [&](const float* buf, const W4& w) {
    const char* Ab = (const char*)buf;
    #pragma unroll
    for (int t = 0; t < 4; ++t) {
      #pragma unroll
      for (int f = 0; f < 8; ++f) {
        const int row = f * 16 + ln15;
        const int swz = (row & 7) << 4;
        const int b0  = t * 128 + kseg * 32;
        float4 lo = *(const float4*)(Ab + row * 512 + ((b0)      ^ swz));
        float4 hi = *(const float4*)(Ab + row * 512 + ((b0 + 16) ^ swz));
        acc[f] = __builtin_amdgcn_mfma_f32_16x16x32_bf16(cvt8(lo, hi), w.t[t],
                                                         acc[f], 0, 0, 0);
      }
    }
  };

  float* A0 = &As[0][0];
  float* A1 = &As[1][0];

  // ---- prologue: chunk 0 in flight ----
  W4 wA = loadw(0);
  stage(A0, 0);

  // ---- main loop: 2 chunks per iteration, static even/odd roles ----
  #pragma unroll 1
  for (int i = 0; i < 15; ++i) {
    const int c = 2 * i;
    W4 wB = loadw(c + 1);
    stage(A1, c + 1);
    WAITVM(20);            // chunk c landed; c+1's 20 ops stay in flight
    BARRIER();
    compute(A0, wA);
    BARRIER();             // all waves done reading A0

    wA = loadw(c + 2);
    stage(A0, c + 2);
    WAITVM(20);
    BARRIER();
    compute(A1, wB);
    BARRIER();
  }
  // ---- tail: chunks 30, 31 ----
  {
    W4 wB = loadw(31);
    stage(A1, 31);
    WAITVM(20);
    BARRIER();
    compute(A0, wA);
    BARRIER();
    WAITVM(0);
    BARRIER();
    compute(A1, wB);
  }

  // ---- epilogue: bounce through LDS for coalesced out stores ----
  // D mapping: col=lane&15 (within group), row=(lane>>4)*4+r (m89).
  // As[0] is free: every wave finished reading it before the last barrier.
  const int col = wave * 16 + ln15;
  const float bv = bias[col];
  #pragma unroll
  for (int f = 0; f < 8; ++f) {
    #pragma unroll
    for (int r = 0; r < 4; ++r)
      A0[(f * 16 + kseg * 4 + r) * N_DIM + col] = acc[f][r] + bv;
  }
  __syncthreads();
  // 128 rows x 64 cols x 4B = 32 KB contiguous at out + m0*64
  float4* og = (float4*)(out + (size_t)m0 * N_DIM);
  const float4* ol = (const float4*)A0;
  #pragma unroll
  for (int p = 0; p < 8; ++p) {
    const int fi = p * 256 + tid;
    og[fi] = ol[fi];
  }
}

extern "C" void kernel_launch(void* const* d_in, const int* in_sizes, int n_in,
                              void* d_out, int out_size, void* d_ws, size_t ws_size,
                              hipStream_t stream) {
  const float* x    = (const float*)d_in[0];
  const float* s    = (const float*)d_in[1];
  const float* a    = (const float*)d_in[2];
  const float* b    = (const float*)d_in[3];
  const float* bias = (const float*)d_in[4];
  float* out = (float*)d_out;
  unsigned short* wF = (unsigned short*)d_ws;   // 512 KB

  build_wF<<<1024, 256, 0, stream>>>(s, a, b, wF);
  kron_gemm<<<BATCH / ROWB, 256, 0, stream>>>(x, wF, bias, out);
}

// Round 9
// 154.307 us; speedup vs baseline: 1.0063x; 1.0063x over previous
//
#include <hip/hip_runtime.h>
#include <hip/hip_bf16.h>

#define RANK 16
#define BATCH 32768
#define K_DIM 4096   // A1*B1
#define N_DIM 64     // A2*B2
#define CHUNK 64     // K floats per chunk = 256B per row
#define NCHUNK 64    // 4096/64
#define ROWB 128     // rows per block

typedef __bf16 bf16x8 __attribute__((ext_vector_type(8)));
typedef float floatx4 __attribute__((ext_vector_type(4)));
typedef unsigned short ushort8 __attribute__((ext_vector_type(8)));

#define WAITVM(n) asm volatile("s_waitcnt vmcnt(" #n ")" ::: "memory")
#define BARRIER() asm volatile("s_barrier" ::: "memory")

__device__ inline unsigned short f2bf(float f) {
  unsigned u = __builtin_bit_cast(unsigned, f);
  u += 0x7fffu + ((u >> 16) & 1u);   // round-to-nearest-even
  return (unsigned short)(u >> 16);
}

__device__ inline bf16x8 cvt8(float4 a0, float4 a1) {
  ushort8 au;
  au[0] = f2bf(a0.x); au[1] = f2bf(a0.y); au[2] = f2bf(a0.z); au[3] = f2bf(a0.w);
  au[4] = f2bf(a1.x); au[5] = f2bf(a1.y); au[6] = f2bf(a1.z); au[7] = f2bf(a1.w);
  return __builtin_bit_cast(bf16x8, au);
}

// Fragment-major w for the 16x16x32 B-operand (layout unchanged):
//   wF[((cg*128 + ks)*64 + lane)*8 + j] = w[k][n],
//   n = cg*16 + (lane&15), k = ks*32 + (lane>>4)*8 + j.
__global__ __launch_bounds__(256) void build_wF(
    const float* __restrict__ s, const float* __restrict__ a,
    const float* __restrict__ b, unsigned short* __restrict__ wF) {
  int e = blockIdx.x * 256 + threadIdx.x;   // 0 .. 262143
  int j    = e & 7;
  int lane = (e >> 3) & 63;
  int ks   = (e >> 9) & 127;
  int cg   = e >> 16;
  int n = cg * 16 + (lane & 15);
  int k = ks * 32 + ((lane >> 4) << 3) + j;
  int i = k >> 6, kk = k & 63, jj = n >> 3, ll = n & 7;
  float acc = 0.f;
  #pragma unroll
  for (int r = 0; r < RANK; ++r) {
    acc += a[r * 512 + i * 8 + jj] * b[r * 512 + kk * 8 + ll];
  }
  acc *= s[i * 8 + jj];
  wF[e] = f2bf(acc);
}

// Block = 128 rows x 64 cols, 8 waves (512 thr) = 2 waves/SIMD at
// 1 block/CU. Wave = (col-group cg, row-half rh): 4 A-frags x 16 cols.
// w staged to LDS once per block per chunk (cooperative, zero
// duplication) -> per-block vmem = x 2MB + w 0.5MB, chip 0.65GB against
// the ~12.5 B/cyc/CU vmem port (r6/r7 model) WITH the 2-waves/SIMD
// latency cover r8 lacked. Counted ring: 5 vmem ops/wave/chunk (4 x-gll
// + 1 w-gll), WAITVM(5) keeps exactly the next chunk in flight; compute
// issues no vmem (A and w both via ds_read). XOR swizzle (16B-unit ^=
// row&15) on global source + ds_read side. Coalesced LDS-bounce
// epilogue.
__global__ __launch_bounds__(512, 1) void kron_gemm(
    const float* __restrict__ x, const unsigned short* __restrict__ wF,
    const float* __restrict__ bias, float* __restrict__ out) {
  __shared__ __align__(16) float          As[2][ROWB * CHUNK];   // 2 x 32 KB
  __shared__ __align__(16) unsigned short Ws[2][8][512];         // 2 x 8 KB

  const int tid  = threadIdx.x;
  const int lane = tid & 63;
  const int wave = tid >> 6;          // 0..7
  const int cg   = wave & 3;          // col-group (compute role)
  const int rh   = wave >> 2;         // row-half (compute role)
  const int ln15 = lane & 15;
  const int kseg = lane >> 4;
  const int m0   = blockIdx.x * ROWB;

  floatx4 acc[4] = {};

  // stage chunk c: 4 x-gll (1KB = 4 rows x 256B) + 1 w-gll per wave
  auto stage = [&](int buf, int c) {
    #pragma unroll
    for (int p = 0; p < 4; ++p) {
      const int rbase = wave * 16 + 4 * p;               // wave-uniform
      const int row   = rbase + (lane >> 4);             // per-lane
      const int sb    = ((lane & 15) << 4) ^ ((row & 15) << 4);
      const float* src = x + (size_t)(m0 + row) * K_DIM + c * CHUNK + (sb >> 2);
      float* dst = &As[buf][rbase * CHUNK];
      __builtin_amdgcn_global_load_lds(
          (const __attribute__((address_space(1))) void*)(const void*)src,
          (__attribute__((address_space(3))) void*)(void*)dst, 16, 0, 0);
    }
    {
      // w piece: staging role (scg, st) independent of compute role
      const int scg = wave >> 1, st = wave & 1;
      const unsigned short* src =
          wF + (((size_t)(scg * 128 + c * 2 + st)) << 9) + (lane << 3);
      unsigned short* dst = &Ws[buf][scg * 2 + st][0];
      __builtin_amdgcn_global_load_lds(
          (const __attribute__((address_space(1))) void*)(const void*)src,
          (__attribute__((address_space(3))) void*)(void*)dst, 16, 0, 0);
    }
  };

  // compute chunk in buffer buf: pure LDS reads + MFMA, no vmem
  auto compute = [&](int buf) {
    const char* Ab = (const char*)&As[buf][0];
    #pragma unroll
    for (int t = 0; t < 2; ++t) {
      bf16x8 wf = *(const bf16x8*)&Ws[buf][cg * 2 + t][lane << 3];
      #pragma unroll
      for (int f = 0; f < 4; ++f) {
        const int row = rh * 64 + f * 16 + ln15;
        const int swz = (row & 15) << 4;                 // = ln15<<4
        const int b0  = t * 128 + kseg * 32;
        float4 lo = *(const float4*)(Ab + row * 256 + ((b0)      ^ swz));
        float4 hi = *(const float4*)(Ab + row * 256 + ((b0 + 16) ^ swz));
        acc[f] = __builtin_amdgcn_mfma_f32_16x16x32_bf16(cvt8(lo, hi), wf,
                                                         acc[f], 0, 0, 0);
      }
    }
  };

  // ---- prologue: chunk 0 in flight ----
  stage(0, 0);

  // ---- main loop: 2 chunks per iteration, static even/odd roles ----
  #pragma unroll 1
  for (int i = 0; i < NCHUNK / 2 - 1; ++i) {
    const int c = 2 * i;
    stage(1, c + 1);
    WAITVM(5);             // chunk c landed; c+1's 5 ops stay in flight
    BARRIER();
    compute(0);
    BARRIER();             // all waves done reading buf 0

    stage(0, c + 2);
    WAITVM(5);
    BARRIER();
    compute(1);
    BARRIER();
  }
  // ---- tail: chunks 62, 63 ----
  {
    stage(1, NCHUNK - 1);
    WAITVM(5);
    BARRIER();
    compute(0);
    BARRIER();
    WAITVM(0);
    BARRIER();
    compute(1);
  }

  // ---- epilogue: bounce through LDS for coalesced out stores ----
  // D mapping: col=lane&15 (in group), row=(lane>>4)*4+r (m89 mapping).
  // As[0] free: all waves passed the barrier after its last read.
  float* A0 = &As[0][0];
  const int col = cg * 16 + ln15;
  const float bv = bias[col];
  #pragma unroll
  for (int f = 0; f < 4; ++f) {
    #pragma unroll
    for (int r = 0; r < 4; ++r)
      A0[(rh * 64 + f * 16 + kseg * 4 + r) * N_DIM + col] = acc[f][r] + bv;
  }
  __syncthreads();
  // 128 rows x 64 cols x 4B = 32 KB contiguous at out + m0*64
  float4* og = (float4*)(out + (size_t)m0 * N_DIM);
  const float4* ol = (const float4*)A0;
  #pragma unroll
  for (int p = 0; p < 4; ++p) {
    const int fi = p * 512 + tid;
    og[fi] = ol[fi];
  }
}

extern "C" void kernel_launch(void* const* d_in, const int* in_sizes, int n_in,
                              void* d_out, int out_size, void* d_ws, size_t ws_size,
                              hipStream_t stream) {
  const float* x    = (const float*)d_in[0];
  const float* s    = (const float*)d_in[1];
  const float* a    = (const float*)d_in[2];
  const float* b    = (const float*)d_in[3];
  const float* bias = (const float*)d_in[4];
  float* out = (float*)d_out;
  unsigned short* wF = (unsigned short*)d_ws;   // 512 KB

  build_wF<<<1024, 256, 0, stream>>>(s, a, b, wF);
  kron_gemm<<<BATCH / ROWB, 512, 0, stream>>>(x, wF, bias, out);
}

// Round 10
// 153.379 us; speedup vs baseline: 1.0124x; 1.0061x over previous
//
#include <hip/hip_runtime.h>
#include <hip/hip_bf16.h>

#define RANK 16
#define BATCH 32768
#define K_DIM 4096   // A1*B1
#define N_DIM 64     // A2*B2
#define CHUNK 64     // K floats per chunk = 256B per row
#define NCHUNK 64    // 4096/64
#define ROWB 64      // rows per block

typedef __bf16 bf16x8 __attribute__((ext_vector_type(8)));
typedef float floatx4 __attribute__((ext_vector_type(4)));
typedef unsigned short ushort8 __attribute__((ext_vector_type(8)));

#define WAITVM(n) asm volatile("s_waitcnt vmcnt(" #n ")" ::: "memory")
#define BARRIER() asm volatile("s_barrier" ::: "memory")

__device__ inline unsigned short f2bf(float f) {
  unsigned u = __builtin_bit_cast(unsigned, f);
  u += 0x7fffu + ((u >> 16) & 1u);   // round-to-nearest-even
  return (unsigned short)(u >> 16);
}

__device__ inline bf16x8 cvt8(float4 a0, float4 a1) {
  ushort8 au;
  au[0] = f2bf(a0.x); au[1] = f2bf(a0.y); au[2] = f2bf(a0.z); au[3] = f2bf(a0.w);
  au[4] = f2bf(a1.x); au[5] = f2bf(a1.y); au[6] = f2bf(a1.z); au[7] = f2bf(a1.w);
  return __builtin_bit_cast(bf16x8, au);
}

// Fragment-major w for the 16x16x32 B-operand (layout unchanged):
//   wF[((cg*128 + ks)*64 + lane)*8 + j] = w[k][n],
//   n = cg*16 + (lane&15), k = ks*32 + (lane>>4)*8 + j.
__global__ __launch_bounds__(256) void build_wF(
    const float* __restrict__ s, const float* __restrict__ a,
    const float* __restrict__ b, unsigned short* __restrict__ wF) {
  int e = blockIdx.x * 256 + threadIdx.x;   // 0 .. 262143
  int j    = e & 7;
  int lane = (e >> 3) & 63;
  int ks   = (e >> 9) & 127;
  int cg   = e >> 16;
  int n = cg * 16 + (lane & 15);
  int k = ks * 32 + ((lane >> 4) << 3) + j;
  int i = k >> 6, kk = k & 63, jj = n >> 3, ll = n & 7;
  float acc = 0.f;
  #pragma unroll
  for (int r = 0; r < RANK; ++r) {
    acc += a[r * 512 + i * 8 + jj] * b[r * 512 + kk * 8 + ll];
  }
  acc *= s[i * 8 + jj];
  wF[e] = f2bf(acc);
}

// Block = 64 rows x 64 cols, 4 waves (wave = one 16-col group x all 64
// rows), 2 blocks/CU — the only structure that has won (r7); r8/r9
// showed single-block/CU barrier domains cost ~30us regardless of byte
// count. New vs r7: depth-2 counted ring (NBUF=4 x 16KB, two chunks
// always in flight; 6 vmem ops/chunk/wave -> WAITVM(12) drains only the
// chunk being computed) to close r7's port-idle gap (6.7 vs 7.4+ TB/s
// demonstrated elsewhere), and the r8-validated coalesced LDS-bounce
// epilogue. Compute issues no vmem; XOR swizzle on global source +
// ds_read side (both-sides rule), r9-verified variant (unit ^= row&15).
__global__ __launch_bounds__(256, 2) void kron_gemm(
    const float* __restrict__ x, const unsigned short* __restrict__ wF,
    const float* __restrict__ bias, float* __restrict__ out) {
  __shared__ __align__(16) float As[4][ROWB * CHUNK];   // 4 x 16 KB

  const int tid  = threadIdx.x;
  const int lane = tid & 63;
  const int wave = tid >> 6;     // = col-group cg
  const int ln15 = lane & 15;
  const int kseg = lane >> 4;
  const int m0   = blockIdx.x * ROWB;

  floatx4 acc[4] = {};

  struct W2 { bf16x8 t[2]; };

  auto loadw = [&](int c) {
    W2 w;
    #pragma unroll
    for (int t = 0; t < 2; ++t)
      w.t[t] = *(const bf16x8*)(wF + (((size_t)(wave * 128 + c * 2 + t)) << 9)
                                + (lane << 3));
    return w;
  };

  // stage chunk c: 4 gll instrs/wave, each 1KB = 4 rows x 256B
  auto stage = [&](int buf, int c) {
    #pragma unroll
    for (int p = 0; p < 4; ++p) {
      const int rbase = wave * 16 + 4 * p;               // wave-uniform
      const int row   = rbase + (lane >> 4);             // per-lane
      const int sb    = ((lane & 15) << 4) ^ ((row & 15) << 4);
      const float* src = x + (size_t)(m0 + row) * K_DIM + c * CHUNK + (sb >> 2);
      float* dst = &As[buf][rbase * CHUNK];
      __builtin_amdgcn_global_load_lds(
          (const __attribute__((address_space(1))) void*)(const void*)src,
          (__attribute__((address_space(3))) void*)(void*)dst, 16, 0, 0);
    }
  };

  auto compute = [&](int buf, const W2& w) {
    const char* Ab = (const char*)&As[buf][0];
    #pragma unroll
    for (int t = 0; t < 2; ++t) {
      #pragma unroll
      for (int f = 0; f < 4; ++f) {
        const int row = f * 16 + ln15;
        const int swz = (row & 15) << 4;                 // = ln15<<4
        const int b0  = t * 128 + kseg * 32;
        float4 lo = *(const float4*)(Ab + row * 256 + ((b0)      ^ swz));
        float4 hi = *(const float4*)(Ab + row * 256 + ((b0 + 16) ^ swz));
        acc[f] = __builtin_amdgcn_mfma_f32_16x16x32_bf16(cvt8(lo, hi), w.t[t],
                                                         acc[f], 0, 0, 0);
      }
    }
  };

  // ---- prologue: chunks 0,1 in flight (12 vmem ops) ----
  W2 w0 = loadw(0); stage(0, 0);
  W2 w1 = loadw(1); stage(1, 1);
  W2 w2, w3;

  // ---- main loop: 4 chunks per iteration, static reg/buf roles ----
  // invariant at top (c = 4i): w0=w(c), w1=w(c+1); chunks c, c+1 in flight
  #pragma unroll 1
  for (int i = 0; i < 15; ++i) {
    const int c = 4 * i;
    w2 = loadw(c + 2); stage(2, c + 2);
    WAITVM(12); BARRIER();           // chunk c landed; c+1,c+2 in flight
    compute(0, w0);
    BARRIER();
    w3 = loadw(c + 3); stage(3, c + 3);
    WAITVM(12); BARRIER();
    compute(1, w1);
    BARRIER();
    w0 = loadw(c + 4); stage(0, c + 4);
    WAITVM(12); BARRIER();
    compute(2, w2);
    BARRIER();
    w1 = loadw(c + 5); stage(1, c + 5);
    WAITVM(12); BARRIER();
    compute(3, w3);
    BARRIER();
  }
  // ---- tail: chunks 60..63 (w0=w(60), w1=w(61); 60,61 in flight) ----
  {
    w2 = loadw(62); stage(2, 62);
    w3 = loadw(63); stage(3, 63);
    WAITVM(18); BARRIER(); compute(0, w0); BARRIER();
    WAITVM(12); BARRIER(); compute(1, w1); BARRIER();
    WAITVM(6);  BARRIER(); compute(2, w2); BARRIER();
    WAITVM(0);  BARRIER(); compute(3, w3);
  }

  // ---- epilogue: bounce through LDS for coalesced out stores ----
  // D mapping: col=lane&15 (in group), row=(lane>>4)*4+r (m89 mapping).
  __syncthreads();
  float* A0 = &As[0][0];
  const int col = wave * 16 + ln15;
  const float bv = bias[col];
  #pragma unroll
  for (int f = 0; f < 4; ++f) {
    #pragma unroll
    for (int r = 0; r < 4; ++r)
      A0[(f * 16 + kseg * 4 + r) * N_DIM + col] = acc[f][r] + bv;
  }
  __syncthreads();
  // 64 rows x 64 cols x 4B = 16 KB contiguous at out + m0*64
  float4* og = (float4*)(out + (size_t)m0 * N_DIM);
  const float4* ol = (const float4*)A0;
  #pragma unroll
  for (int p = 0; p < 4; ++p) {
    const int fi = p * 256 + tid;
    og[fi] = ol[fi];
  }
}

extern "C" void kernel_launch(void* const* d_in, const int* in_sizes, int n_in,
                              void* d_out, int out_size, void* d_ws, size_t ws_size,
                              hipStream_t stream) {
  const float* x    = (const float*)d_in[0];
  const float* s    = (const float*)d_in[1];
  const float* a    = (const float*)d_in[2];
  const float* b    = (const float*)d_in[3];
  const float* bias = (const float*)d_in[4];
  float* out = (float*)d_out;
  unsigned short* wF = (unsigned short*)d_ws;   // 512 KB

  build_wF<<<1024, 256, 0, stream>>>(s, a, b, wF);
  kron_gemm<<<BATCH / ROWB, 256, 0, stream>>>(x, wF, bias, out);
}

// Round 11
// 132.245 us; speedup vs baseline: 1.1742x; 1.1598x over previous
//
#include <hip/hip_runtime.h>
#include <hip/hip_bf16.h>

#define RANK 16
#define BATCH 32768
#define K_DIM 4096   // A1*B1
#define N_DIM 64     // A2*B2
#define CHUNK 128    // K floats per chunk = 512B per row (proven run length)
#define NCHUNK 32    // 4096/128
#define ROWB 128     // rows per block (w amortized via LDS)

typedef __bf16 bf16x8 __attribute__((ext_vector_type(8)));
typedef float floatx4 __attribute__((ext_vector_type(4)));
typedef unsigned short ushort8 __attribute__((ext_vector_type(8)));

#define WAITVM(n) asm volatile("s_waitcnt vmcnt(" #n ")" ::: "memory")
#define BARRIER() asm volatile("s_barrier" ::: "memory")

__device__ inline unsigned short f2bf(float f) {
  unsigned u = __builtin_bit_cast(unsigned, f);
  u += 0x7fffu + ((u >> 16) & 1u);   // round-to-nearest-even
  return (unsigned short)(u >> 16);
}

__device__ inline bf16x8 cvt8(float4 a0, float4 a1) {
  ushort8 au;
  au[0] = f2bf(a0.x); au[1] = f2bf(a0.y); au[2] = f2bf(a0.z); au[3] = f2bf(a0.w);
  au[4] = f2bf(a1.x); au[5] = f2bf(a1.y); au[6] = f2bf(a1.z); au[7] = f2bf(a1.w);
  return __builtin_bit_cast(bf16x8, au);
}

// Fragment-major w for the 16x16x32 B-operand (layout unchanged):
//   wF[((cg*128 + ks)*64 + lane)*8 + j] = w[k][n],
//   n = cg*16 + (lane&15), k = ks*32 + (lane>>4)*8 + j.
__global__ __launch_bounds__(256) void build_wF(
    const float* __restrict__ s, const float* __restrict__ a,
    const float* __restrict__ b, unsigned short* __restrict__ wF) {
  int e = blockIdx.x * 256 + threadIdx.x;   // 0 .. 262143
  int j    = e & 7;
  int lane = (e >> 3) & 63;
  int ks   = (e >> 9) & 127;
  int cg   = e >> 16;
  int n = cg * 16 + (lane & 15);
  int k = ks * 32 + ((lane >> 4) << 3) + j;
  int i = k >> 6, kk = k & 63, jj = n >> 3, ll = n & 7;
  float acc = 0.f;
  #pragma unroll
  for (int r = 0; r < RANK; ++r) {
    acc += a[r * 512 + i * 8 + jj] * b[r * 512 + kk * 8 + ll];
  }
  acc *= s[i * 8 + jj];
  wF[e] = f2bf(acc);
}

// Round-11 isolation: r9 with ONE variable flipped (CHUNK 64->128).
// Cross-round matrix says run length is dominant (every 256B-run kernel
// = 153-155us regardless of structure; 512B-run kernels with >=2
// waves/SIMD = 121-138us), and bytes are the second lever (r6->r7).
// This is the only untested cell: 512B runs + shared-w 0.65GB +
// 2 waves/SIMD. Block = 128 rows x 64 cols, 8 waves = (cg, rh); x AND w
// staged via global_load_lds (contiguous 1KB instrs); counted ring:
// 10 gll/wave/chunk (8 x + 2 w), WAITVM(10) keeps the next chunk in
// flight; compute phase is vmem-free. XOR swizzle (16B-unit ^= row&7)
// on global source + ds_read side. LDS = 2x64KB As + 2x16KB Ws =
// exactly 160KB. Coalesced LDS-bounce epilogue.
__global__ __launch_bounds__(512, 1) void kron_gemm(
    const float* __restrict__ x, const unsigned short* __restrict__ wF,
    const float* __restrict__ bias, float* __restrict__ out) {
  __shared__ __align__(16) float          As[2][ROWB * CHUNK];  // 2 x 64 KB
  __shared__ __align__(16) unsigned short Ws[2][16][512];       // 2 x 16 KB

  const int tid   = threadIdx.x;
  const int lane  = tid & 63;
  const int wave  = tid >> 6;         // 0..7
  const int cg    = wave & 3;         // col-group (compute role)
  const int rh    = wave >> 2;        // row-half (compute role)
  const int ln15  = lane & 15;
  const int kseg  = lane >> 4;
  const int rhalf = lane >> 5;        // staging: row within the 1KB pair
  const int m0    = blockIdx.x * ROWB;

  floatx4 acc[4] = {};

  // stage chunk c: 8 x-gll (1KB = 2 rows x 512B) + 2 w-gll per wave
  auto stage = [&](int buf, int c) {
    #pragma unroll
    for (int p = 0; p < 8; ++p) {
      const int rbase = wave * 16 + 2 * p;               // wave-uniform
      const int row   = rbase + rhalf;                   // per-lane
      const int sb    = ((lane & 31) << 4) ^ ((row & 7) << 4);
      const float* src = x + (size_t)(m0 + row) * K_DIM + c * CHUNK + (sb >> 2);
      float* dst = &As[buf][rbase * CHUNK];
      __builtin_amdgcn_global_load_lds(
          (const __attribute__((address_space(1))) void*)(const void*)src,
          (__attribute__((address_space(3))) void*)(void*)dst, 16, 0, 0);
    }
    #pragma unroll
    for (int p = 0; p < 2; ++p) {
      const int idx = wave * 2 + p;                      // 0..15 = scg*4+st
      const unsigned short* src =
          wF + (((size_t)((idx >> 2) * 128 + c * 4 + (idx & 3))) << 9)
             + (lane << 3);
      unsigned short* dst = &Ws[buf][idx][0];
      __builtin_amdgcn_global_load_lds(
          (const __attribute__((address_space(1))) void*)(const void*)src,
          (__attribute__((address_space(3))) void*)(void*)dst, 16, 0, 0);
    }
  };

  // compute chunk in buffer buf: pure LDS reads + MFMA, no vmem
  auto compute = [&](int buf) {
    const char* Ab = (const char*)&As[buf][0];
    #pragma unroll
    for (int t = 0; t < 4; ++t) {
      bf16x8 wf = *(const bf16x8*)&Ws[buf][cg * 4 + t][lane << 3];
      #pragma unroll
      for (int f = 0; f < 4; ++f) {
        const int row = rh * 64 + f * 16 + ln15;
        const int swz = (row & 7) << 4;
        const int b0  = t * 128 + kseg * 32;
        float4 lo = *(const float4*)(Ab + row * 512 + ((b0)      ^ swz));
        float4 hi = *(const float4*)(Ab + row * 512 + ((b0 + 16) ^ swz));
        acc[f] = __builtin_amdgcn_mfma_f32_16x16x32_bf16(cvt8(lo, hi), wf,
                                                         acc[f], 0, 0, 0);
      }
    }
  };

  // ---- prologue: chunk 0 in flight ----
  stage(0, 0);

  // ---- main loop: 2 chunks per iteration, static even/odd roles ----
  #pragma unroll 1
  for (int i = 0; i < NCHUNK / 2 - 1; ++i) {
    const int c = 2 * i;
    stage(1, c + 1);
    WAITVM(10);            // chunk c landed; c+1's 10 ops stay in flight
    BARRIER();
    compute(0);
    BARRIER();             // all waves done reading buf 0

    stage(0, c + 2);
    WAITVM(10);
    BARRIER();
    compute(1);
    BARRIER();
  }
  // ---- tail: chunks 30, 31 ----
  {
    stage(1, NCHUNK - 1);
    WAITVM(10);
    BARRIER();
    compute(0);
    BARRIER();
    WAITVM(0);
    BARRIER();
    compute(1);
  }

  // ---- epilogue: bounce through LDS for coalesced out stores ----
  // D mapping: col=lane&15 (in group), row=(lane>>4)*4+r (m89 mapping).
  // As[0] is safe to overwrite: all waves passed the barrier after its
  // last read (compute(0) of chunk 30).
  float* A0 = &As[0][0];
  const int col = cg * 16 + ln15;
  const float bv = bias[col];
  #pragma unroll
  for (int f = 0; f < 4; ++f) {
    #pragma unroll
    for (int r = 0; r < 4; ++r)
      A0[(rh * 64 + f * 16 + kseg * 4 + r) * N_DIM + col] = acc[f][r] + bv;
  }
  __syncthreads();
  // 128 rows x 64 cols x 4B = 32 KB contiguous at out + m0*64
  float4* og = (float4*)(out + (size_t)m0 * N_DIM);
  const float4* ol = (const float4*)A0;
  #pragma unroll
  for (int p = 0; p < 4; ++p) {
    const int fi = p * 512 + tid;
    og[fi] = ol[fi];
  }
}

extern "C" void kernel_launch(void* const* d_in, const int* in_sizes, int n_in,
                              void* d_out, int out_size, void* d_ws, size_t ws_size,
                              hipStream_t stream) {
  const float* x    = (const float*)d_in[0];
  const float* s    = (const float*)d_in[1];
  const float* a    = (const float*)d_in[2];
  const float* b    = (const float*)d_in[3];
  const float* bias = (const float*)d_in[4];
  float* out = (float*)d_out;
  unsigned short* wF = (unsigned short*)d_ws;   // 512 KB

  build_wF<<<1024, 256, 0, stream>>>(s, a, b, wF);
  kron_gemm<<<BATCH / ROWB, 512, 0, stream>>>(x, wF, bias, out);
}